// Round 14
// baseline (174.450 us; speedup 1.0000x reference)
//
#include <hip/hip_runtime.h>
#include <cstdint>
#include <cstddef>

typedef unsigned long long u64;

#define B_SZ 4096
#define C_SZ 1000
#define V_SZ 8000
#define RW 128              // padded row stride in u64 (125 used, rest zero)
#define THRESHF 0.8f
#define SCALEF 0.1f

#define OFF_CI 0
#define OFF_CS (B_SZ * 5)
#define OFF_HI (2 * B_SZ * 5)
#define OFF_HS (3 * B_SZ * 5)
#define OFF_C1 (3 * B_SZ * 5 + B_SZ)
#define OFF_C2 (3 * B_SZ * 5 + 2 * B_SZ)

// ---------------- pack matrix rows into bitmasks ----------------
__global__ __launch_bounds__(256) void pack_kernel(const int* __restrict__ mat,
                                                   u64* __restrict__ packed) {
  const int c = blockIdx.x;
  const int tid = threadIdx.x;
  const int lane = tid & 63;
  const int wv = tid >> 6;
  const int* row = mat + (size_t)c * V_SZ;
  for (int base = 0; base < 8192; base += 256) {
    const int k = base + tid;
    int v = 0;
    if (k < V_SZ) v = row[k];
    u64 msk = __ballot(v != 0);
    if (lane == 0) packed[(size_t)c * RW + ((base >> 6) + wv)] = msk;
  }
}

// ---------------- class softmax + top5 (plain float4 loads - R9 verbatim) ----------------
__global__ __launch_bounds__(256) void class_topk_kernel(const float* __restrict__ logits,
                                                         float* __restrict__ out) {
  const int b = blockIdx.x;
  const int tid = threadIdx.x;
  const int lane = tid & 63;
  const int wv = tid >> 6;
  const float* row = logits + (size_t)b * V_SZ;
  float v[32];
#pragma unroll
  for (int f = 0; f < 8; ++f) {
    const int base = (f << 10) + (tid << 2);
    if (base < V_SZ) {
      float4 x = *(const float4*)(row + base);
      v[4 * f + 0] = x.x; v[4 * f + 1] = x.y; v[4 * f + 2] = x.z; v[4 * f + 3] = x.w;
    } else {
      v[4 * f + 0] = -INFINITY; v[4 * f + 1] = -INFINITY;
      v[4 * f + 2] = -INFINITY; v[4 * f + 3] = -INFINITY;
    }
  }
  __shared__ float sred[4];
  __shared__ int sredi[4];
  float lm = -INFINITY;
#pragma unroll
  for (int q = 0; q < 32; ++q) lm = fmaxf(lm, v[q]);
#pragma unroll
  for (int o = 32; o >= 1; o >>= 1) lm = fmaxf(lm, __shfl_xor(lm, o));
  if (lane == 0) sred[wv] = lm;
  __syncthreads();
  const float m = fmaxf(fmaxf(sred[0], sred[1]), fmaxf(sred[2], sred[3]));
  float ls = 0.f;
#pragma unroll
  for (int q = 0; q < 32; ++q) ls += expf(v[q] - m);
#pragma unroll
  for (int o = 32; o >= 1; o >>= 1) ls += __shfl_xor(ls, o);
  __syncthreads();
  if (lane == 0) sred[wv] = ls;
  __syncthreads();
  const float ssum = sred[0] + sred[1] + sred[2] + sred[3];
  for (int r = 0; r < 5; ++r) {
    float bv = -INFINITY;
    int bi = 0;
#pragma unroll
    for (int q = 0; q < 32; ++q) {
      const int idx = ((q >> 2) << 10) + (tid << 2) + (q & 3);
      if (v[q] > bv) { bv = v[q]; bi = idx; }
    }
#pragma unroll
    for (int o = 32; o >= 1; o >>= 1) {
      float ov = __shfl_xor(bv, o);
      int oi = __shfl_xor(bi, o);
      if (ov > bv || (ov == bv && oi < bi)) { bv = ov; bi = oi; }
    }
    __syncthreads();
    if (lane == 0) { sred[wv] = bv; sredi[wv] = bi; }
    __syncthreads();
    bv = sred[0]; bi = sredi[0];
#pragma unroll
    for (int w = 1; w < 4; ++w) {
      if (sred[w] > bv || (sred[w] == bv && sredi[w] < bi)) { bv = sred[w]; bi = sredi[w]; }
    }
    if (((bi & 1023) >> 2) == tid) {
      const int sl = ((bi >> 10) << 2) | (bi & 3);
#pragma unroll
      for (int q = 0; q < 32; ++q)
        if (q == sl) v[q] = -INFINITY;
    }
    if (tid == 0) {
      out[OFF_CI + b * 5 + r] = (float)bi;
      out[OFF_CS + b * 5 + r] = expf(bv - m) / ssum;
    }
  }
}

// ---------------- decode: TWO waves per sample (half-columns each) ----------------
// Wave pair (2*sp, 2*sp+1) owns sample b: even wave cols [0,512), odd [512,1000).
// 8192 waves total -> ~24 waves/CU (vs 16) for more outstanding L2/L3 misses.
__global__ __launch_bounds__(256, 6) void decode_kernel(const float* __restrict__ compo_logits,
                                                        const float* __restrict__ co_occ,
                                                        const u64* __restrict__ packed,
                                                        float* __restrict__ out) {
  const int tid = threadIdx.x;
  const int lane = tid & 63;
  const int w = tid >> 6;
  const int sp = w >> 1;          // local sample 0..1
  const int h = w & 1;            // column half
  const int b = blockIdx.x * 2 + sp;
  __shared__ short s_idx[2][512];
  __shared__ float s_val[2][512];
  __shared__ float s_fin[2][1024];
  __shared__ int s_n[2];

  // ---- phase A: full-row sigmoid into regs (both waves of the pair) ----
  const float* lg = compo_logits + (size_t)b * C_SZ;
  float raw[16];
#pragma unroll
  for (int p = 0; p < 4; ++p) {
    const int fi = lane + (p << 6);
    if (fi < 250) {
      float4 x = *(const float4*)(lg + (fi << 2));
      raw[4 * p + 0] = 1.0f / (1.0f + expf(-x.x));
      raw[4 * p + 1] = 1.0f / (1.0f + expf(-x.y));
      raw[4 * p + 2] = 1.0f / (1.0f + expf(-x.z));
      raw[4 * p + 3] = 1.0f / (1.0f + expf(-x.w));
    } else {
      raw[4 * p + 0] = 0.f; raw[4 * p + 1] = 0.f; raw[4 * p + 2] = 0.f; raw[4 * p + 3] = 0.f;
    }
  }
  // ---- phase B: even wave builds the (idx, score) list; static raw[] idx ----
  if (h == 0) {
    int n = 0;
#pragma unroll
    for (int p = 0; p < 4; ++p) {
      unsigned mb = 0;
      if (raw[4 * p + 0] > THRESHF) mb |= 1u;
      if (raw[4 * p + 1] > THRESHF) mb |= 2u;
      if (raw[4 * p + 2] > THRESHF) mb |= 4u;
      if (raw[4 * p + 3] > THRESHF) mb |= 8u;
      const int cnt = __popc(mb);
      int inc = cnt;
#pragma unroll
      for (int o = 1; o < 64; o <<= 1) {
        int t = __shfl_up(inc, o);
        if (lane >= o) inc += t;
      }
      int off = n + inc - cnt;
      const int total = __shfl(inc, 63);
#pragma unroll
      for (int j = 0; j < 4; ++j) {
        if (mb & (1u << j)) {
          s_idx[sp][off] = (short)((p << 8) + (lane << 2) + j);
          s_val[sp][off] = raw[4 * p + j];
          ++off;
        }
      }
      n += total;
    }
    if (lane < 4) { s_idx[sp][n + lane] = 0; s_val[sp][n + lane] = 0.0f; }  // m=0 pad
    if (lane == 0) s_n[sp] = n;
  }
  __syncthreads();
  const int n = s_n[sp];

  // ---- phase C: half-column matvec, 4 rows/iter (8 loads in flight) ----
  float4 accA = {0, 0, 0, 0}, accB = {0, 0, 0, 0};
  {
    const float4* cop = (const float4*)co_occ;
    const int f4a = (h << 7) + lane;          // h0: lane (p0)      | h1: 128+lane (p2)
    const int f4b = f4a + 64;                 // h0: 64+lane (p1)   | h1: 192+lane (p3)
    const bool gb = (h == 0) || (lane < 58);
    for (int e = 0; e < n; e += 4) {
      const int i0 = s_idx[sp][e + 0]; const float m0 = s_val[sp][e + 0];
      const int i1 = s_idx[sp][e + 1]; const float m1 = s_val[sp][e + 1];
      const int i2 = s_idx[sp][e + 2]; const float m2 = s_val[sp][e + 2];
      const int i3 = s_idx[sp][e + 3]; const float m3 = s_val[sp][e + 3];
      const float4* r0 = cop + (size_t)i0 * 250;
      const float4* r1 = cop + (size_t)i1 * 250;
      const float4* r2 = cop + (size_t)i2 * 250;
      const float4* r3 = cop + (size_t)i3 * 250;
      float4 a0 = r0[f4a], b0 = r1[f4a], d0 = r2[f4a], e0 = r3[f4a];
      float4 a1 = {0, 0, 0, 0}, b1 = {0, 0, 0, 0}, d1 = {0, 0, 0, 0}, e1 = {0, 0, 0, 0};
      if (gb) { a1 = r0[f4b]; b1 = r1[f4b]; d1 = r2[f4b]; e1 = r3[f4b]; }
      accA.x += m0 * a0.x; accA.y += m0 * a0.y; accA.z += m0 * a0.z; accA.w += m0 * a0.w;
      accB.x += m0 * a1.x; accB.y += m0 * a1.y; accB.z += m0 * a1.z; accB.w += m0 * a1.w;
      accA.x += m1 * b0.x; accA.y += m1 * b0.y; accA.z += m1 * b0.z; accA.w += m1 * b0.w;
      accB.x += m1 * b1.x; accB.y += m1 * b1.y; accB.z += m1 * b1.z; accB.w += m1 * b1.w;
      accA.x += m2 * d0.x; accA.y += m2 * d0.y; accA.z += m2 * d0.z; accA.w += m2 * d0.w;
      accB.x += m2 * d1.x; accB.y += m2 * d1.y; accB.z += m2 * d1.z; accB.w += m2 * d1.w;
      accA.x += m3 * e0.x; accA.y += m3 * e0.y; accA.z += m3 * e0.z; accA.w += m3 * e0.w;
      accB.x += m3 * e1.x; accB.y += m3 * e1.y; accB.z += m3 * e1.z; accB.w += m3 * e1.w;
    }
  }
  // ---- phase D: fin for own half -> LDS (static raw[] indices per h branch) ----
  if (h == 0) {
    float4 oA, oB;
    oA.x = raw[0] + SCALEF * accA.x; oA.y = raw[1] + SCALEF * accA.y;
    oA.z = raw[2] + SCALEF * accA.z; oA.w = raw[3] + SCALEF * accA.w;
    oB.x = raw[4] + SCALEF * accB.x; oB.y = raw[5] + SCALEF * accB.y;
    oB.z = raw[6] + SCALEF * accB.z; oB.w = raw[7] + SCALEF * accB.w;
    *(float4*)&s_fin[sp][(lane << 2)] = oA;
    *(float4*)&s_fin[sp][256 + (lane << 2)] = oB;
  } else {
    float4 oA, oB;
    oA.x = raw[8] + SCALEF * accA.x;  oA.y = raw[9] + SCALEF * accA.y;
    oA.z = raw[10] + SCALEF * accA.z; oA.w = raw[11] + SCALEF * accA.w;
    oB.x = raw[12] + SCALEF * accB.x; oB.y = raw[13] + SCALEF * accB.y;
    oB.z = raw[14] + SCALEF * accB.z; oB.w = raw[15] + SCALEF * accB.w;
    *(float4*)&s_fin[sp][512 + (lane << 2)] = oA;
    if (lane < 58) *(float4*)&s_fin[sp][768 + (lane << 2)] = oB;
  }
  __syncthreads();
  if (h == 1) return;   // odd wave done; no further barriers below

  // ---- tail (R4-verbatim layout: col = lane + 64q), scores from LDS ----
  u64 key[16];
  unsigned avail = 0;
  int cnt = 0;
  u64 kb = 0;
#pragma unroll
  for (int q = 0; q < 16; ++q) {
    const int col = lane + (q << 6);
    if (col < C_SZ) {
      const float s = s_fin[sp][col];
      const u64 k = ((u64)__float_as_uint(s) << 32) | (u64)(0xFFFFFFFFu - (unsigned)col);
      key[q] = k;
      if (k > kb) kb = k;
      if (s > THRESHF) { avail |= 1u << q; cnt++; }
    } else key[q] = 0;
  }
  u64 mk = kb;
#pragma unroll
  for (int o = 32; o >= 1; o >>= 1) { u64 t = __shfl_xor(mk, o); if (t > mk) mk = t; }
  const float mxv = __uint_as_float((unsigned)(mk >> 32));
  const int mxi = (int)(0xFFFFFFFFu - (unsigned)(mk & 0xFFFFFFFFull));
#pragma unroll
  for (int o = 32; o >= 1; o >>= 1) cnt += __shfl_xor(cnt, o);
  const int nsel = cnt;
  if ((mxi & 63) == lane) avail &= ~(1u << (mxi >> 6));
  const u64* pr = packed + (size_t)mxi * RW;
  u64 h0 = pr[lane], h1 = pr[64 + lane];
  int pc = __popcll(h0) + __popcll(h1);
#pragma unroll
  for (int o = 32; o >= 1; o >>= 1) pc += __shfl_xor(pc, o);
  int i = 1;
  float last_val = mxv;
  if (nsel >= 2 && pc > 1) {
    for (;;) {
      int kt = (nsel - i < 8) ? (nsel - i) : 8;
      float cval[8];
      int cidx[8];
      u64 rl[8], rh[8];
      float lastc = last_val;
      int kv = 0;
#pragma unroll
      for (int k = 0; k < 8; ++k) {
        cval[k] = 0.0f; cidx[k] = -1;
        if (k < kt) {
          u64 lm = 0;
#pragma unroll
          for (int q = 0; q < 16; ++q)
            if (avail & (1u << q)) { if (key[q] > lm) lm = key[q]; }
          u64 ck = lm;
#pragma unroll
          for (int o = 32; o >= 1; o >>= 1) { u64 t = __shfl_xor(ck, o); if (t > ck) ck = t; }
          if (ck != 0) {
            cval[k] = __uint_as_float((unsigned)(ck >> 32));
            cidx[k] = (int)(0xFFFFFFFFu - (unsigned)(ck & 0xFFFFFFFFull));
            if ((cidx[k] & 63) == lane) avail &= ~(1u << (cidx[k] >> 6));
            lastc = cval[k];
            kv = k + 1;
          }
        }
      }
      kt = kv;
      if (kt == 0) break;
#pragma unroll
      for (int k = 0; k < 8; ++k) {
        if (k < kt) {
          const u64* rp = packed + (size_t)cidx[k] * RW;
          rl[k] = rp[lane]; rh[k] = rp[64 + lane];
        } else { rl[k] = ~0ull; rh[k] = ~0ull; }
      }
      u64 c0 = h0, c1 = h1, pk0 = 0, pk1 = 0;
#pragma unroll
      for (int k = 0; k < 8; ++k) {
        c0 &= rl[k]; c1 &= rh[k];
        const u64 p = (u64)(__popcll(c0) + __popcll(c1));
        if (k < 4) pk0 |= p << (k * 16); else pk1 |= p << ((k - 4) * 16);
      }
#pragma unroll
      for (int o = 32; o >= 1; o >>= 1) { pk0 += __shfl_xor(pk0, o); pk1 += __shfl_xor(pk1, o); }
      int kstar = -1;
      unsigned pcv = 0;
#pragma unroll
      for (int k = 0; k < 8; ++k) {
        if (k < kt && kstar < 0) {
          const unsigned f = (unsigned)(((k < 4 ? pk0 : pk1) >> ((k & 3) * 16)) & 0xFFFFull);
          if (f <= 1u) { kstar = k; pcv = f; }
        }
      }
      if (kstar >= 0) {
        float vk = 0.f, vkm1 = last_val;
#pragma unroll
        for (int k = 0; k < 8; ++k)
          if (k == kstar) { vk = cval[k]; if (k > 0) vkm1 = cval[k - 1]; }
        const int na = (pcv == 1u) ? (kstar + 1) : kstar;
#pragma unroll
        for (int k = 0; k < 8; ++k) if (k < na) { h0 &= rl[k]; h1 &= rh[k]; }
        if (pcv == 1u) { i += kstar + 1; last_val = vk; }
        else { i += kstar; last_val = vkm1; }
        break;
      }
#pragma unroll
      for (int k = 0; k < 8; ++k) if (k < kt) { h0 &= rl[k]; h1 &= rh[k]; }
      i += kt;
      last_val = lastc;
      if (i >= nsel) break;
    }
  }
  const float hit_score = (i == 1) ? mxv : last_val;

  const int c0n = __popcll(h0), c1n = __popcll(h1);
  int s0 = c0n;
#pragma unroll
  for (int o = 1; o < 64; o <<= 1) {
    int nn = __shfl_up(s0, o);
    if (lane >= o) s0 += nn;
  }
  const int tot0 = __shfl(s0, 63);
  const int pre0 = s0 - c0n;
  int s1 = c1n;
#pragma unroll
  for (int o = 1; o < 64; o <<= 1) {
    int nn = __shfl_up(s1, o);
    if (lane >= o) s1 += nn;
  }
  const int tot = tot0 + __shfl(s1, 63);
  const int pre1 = tot0 + s1 - c1n;
  {
    u64 x = h0;
    int r = pre0;
    while (x && r < 5) {
      const int bp = __ffsll((unsigned long long)x) - 1;
      out[OFF_HI + b * 5 + r] = (float)((lane << 6) + bp);
      x &= x - 1;
      ++r;
    }
    x = h1;
    r = pre1;
    while (x && r < 5) {
      const int bp = __ffsll((unsigned long long)x) - 1;
      out[OFF_HI + b * 5 + r] = (float)(((64 + lane) << 6) + bp);
      x &= x - 1;
      ++r;
    }
  }
  int fb = 0x7fffffff;
  if (c0n) fb = (lane << 6) + __ffsll((unsigned long long)h0) - 1;
  else if (c1n) fb = ((64 + lane) << 6) + __ffsll((unsigned long long)h1) - 1;
#pragma unroll
  for (int o = 32; o >= 1; o >>= 1) fb = min(fb, __shfl_xor(fb, o));
  if (lane == 0) {
    const int num_hit = tot < 5 ? tot : 5;
    for (int r = num_hit; r < 5; ++r) out[OFF_HI + b * 5 + r] = -1.0f;
    out[OFF_HS + b] = hit_score;
    const float ci0 = out[OFF_CI + b * 5];
    const float cs0 = out[OFF_CS + b * 5];
    out[OFF_C1 + b] = (num_hit == 1) ? (float)fb : ci0;
    out[OFF_C2 + b] = (cs0 < 0.85f && num_hit == 1) ? (float)fb : ci0;
  }
}

extern "C" void kernel_launch(void* const* d_in, const int* in_sizes, int n_in,
                              void* d_out, int out_size, void* d_ws, size_t ws_size,
                              hipStream_t stream) {
  (void)in_sizes; (void)n_in; (void)out_size; (void)ws_size;
  const float* class_logits = (const float*)d_in[0];
  const float* compo_logits = (const float*)d_in[1];
  const float* co_occ = (const float*)d_in[2];
  const int* mat = (const int*)d_in[3];
  float* out = (float*)d_out;
  u64* packed = (u64*)d_ws;  // 1 MB

  pack_kernel<<<C_SZ, 256, 0, stream>>>(mat, packed);
  class_topk_kernel<<<B_SZ, 256, 0, stream>>>(class_logits, out);
  decode_kernel<<<B_SZ / 2, 256, 0, stream>>>(compo_logits, co_occ, packed, out);
}

// Round 15
// 158.451 us; speedup vs baseline: 1.1010x; 1.1010x over previous
//
#include <hip/hip_runtime.h>
#include <cstdint>
#include <cstddef>

typedef unsigned long long u64;

#define B_SZ 4096
#define C_SZ 1000
#define V_SZ 8000
#define RW 128              // padded row stride in u64 (125 used, rest zero)
#define THRESHF 0.8f
#define SCALEF 0.1f

#define OFF_CI 0
#define OFF_CS (B_SZ * 5)
#define OFF_HI (2 * B_SZ * 5)
#define OFF_HS (3 * B_SZ * 5)
#define OFF_C1 (3 * B_SZ * 5 + B_SZ)
#define OFF_C2 (3 * B_SZ * 5 + 2 * B_SZ)

// ---------------- pack matrix rows into bitmasks ----------------
__global__ __launch_bounds__(256) void pack_kernel(const int* __restrict__ mat,
                                                   u64* __restrict__ packed) {
  const int c = blockIdx.x;
  const int tid = threadIdx.x;
  const int lane = tid & 63;
  const int wv = tid >> 6;
  const int* row = mat + (size_t)c * V_SZ;
  for (int base = 0; base < 8192; base += 256) {
    const int k = base + tid;
    int v = 0;
    if (k < V_SZ) v = row[k];
    u64 msk = __ballot(v != 0);
    if (lane == 0) packed[(size_t)c * RW + ((base >> 6) + wv)] = msk;
  }
}

// ---------------- class softmax + top5 (plain float4 loads - R9 verbatim) ----------------
__global__ __launch_bounds__(256) void class_topk_kernel(const float* __restrict__ logits,
                                                         float* __restrict__ out) {
  const int b = blockIdx.x;
  const int tid = threadIdx.x;
  const int lane = tid & 63;
  const int wv = tid >> 6;
  const float* row = logits + (size_t)b * V_SZ;
  float v[32];
#pragma unroll
  for (int f = 0; f < 8; ++f) {
    const int base = (f << 10) + (tid << 2);
    if (base < V_SZ) {
      float4 x = *(const float4*)(row + base);
      v[4 * f + 0] = x.x; v[4 * f + 1] = x.y; v[4 * f + 2] = x.z; v[4 * f + 3] = x.w;
    } else {
      v[4 * f + 0] = -INFINITY; v[4 * f + 1] = -INFINITY;
      v[4 * f + 2] = -INFINITY; v[4 * f + 3] = -INFINITY;
    }
  }
  __shared__ float sred[4];
  __shared__ int sredi[4];
  float lm = -INFINITY;
#pragma unroll
  for (int q = 0; q < 32; ++q) lm = fmaxf(lm, v[q]);
#pragma unroll
  for (int o = 32; o >= 1; o >>= 1) lm = fmaxf(lm, __shfl_xor(lm, o));
  if (lane == 0) sred[wv] = lm;
  __syncthreads();
  const float m = fmaxf(fmaxf(sred[0], sred[1]), fmaxf(sred[2], sred[3]));
  float ls = 0.f;
#pragma unroll
  for (int q = 0; q < 32; ++q) ls += expf(v[q] - m);
#pragma unroll
  for (int o = 32; o >= 1; o >>= 1) ls += __shfl_xor(ls, o);
  __syncthreads();
  if (lane == 0) sred[wv] = ls;
  __syncthreads();
  const float ssum = sred[0] + sred[1] + sred[2] + sred[3];
  for (int r = 0; r < 5; ++r) {
    float bv = -INFINITY;
    int bi = 0;
#pragma unroll
    for (int q = 0; q < 32; ++q) {
      const int idx = ((q >> 2) << 10) + (tid << 2) + (q & 3);
      if (v[q] > bv) { bv = v[q]; bi = idx; }
    }
#pragma unroll
    for (int o = 32; o >= 1; o >>= 1) {
      float ov = __shfl_xor(bv, o);
      int oi = __shfl_xor(bi, o);
      if (ov > bv || (ov == bv && oi < bi)) { bv = ov; bi = oi; }
    }
    __syncthreads();
    if (lane == 0) { sred[wv] = bv; sredi[wv] = bi; }
    __syncthreads();
    bv = sred[0]; bi = sredi[0];
#pragma unroll
    for (int w = 1; w < 4; ++w) {
      if (sred[w] > bv || (sred[w] == bv && sredi[w] < bi)) { bv = sred[w]; bi = sredi[w]; }
    }
    if (((bi & 1023) >> 2) == tid) {
      const int sl = ((bi >> 10) << 2) | (bi & 3);
#pragma unroll
      for (int q = 0; q < 32; ++q)
        if (q == sl) v[q] = -INFINITY;
    }
    if (tid == 0) {
      out[OFF_CI + b * 5 + r] = (float)bi;
      out[OFF_CS + b * 5 + r] = expf(bv - m) / ssum;
    }
  }
}

// ---------------- decode: TWO waves per sample (half-columns each), spill-free ----------------
// (256,5): VGPR cap 102 (no spill at ~70 live), 20 waves/CU vs R9's 16.
// 3-row batch keeps 6 float4 in flight (24 VGPR) per wave.
__global__ __launch_bounds__(256, 5) void decode_kernel(const float* __restrict__ compo_logits,
                                                        const float* __restrict__ co_occ,
                                                        const u64* __restrict__ packed,
                                                        float* __restrict__ out) {
  const int tid = threadIdx.x;
  const int lane = tid & 63;
  const int w = tid >> 6;
  const int sp = w >> 1;          // local sample 0..1
  const int h = w & 1;            // column half
  const int b = blockIdx.x * 2 + sp;
  __shared__ short s_idx[2][512];
  __shared__ float s_val[2][512];
  __shared__ float s_fin[2][1024];
  __shared__ int s_n[2];

  // ---- phase A: full-row sigmoid into regs (both waves of the pair) ----
  const float* lg = compo_logits + (size_t)b * C_SZ;
  float raw[16];
#pragma unroll
  for (int p = 0; p < 4; ++p) {
    const int fi = lane + (p << 6);
    if (fi < 250) {
      float4 x = *(const float4*)(lg + (fi << 2));
      raw[4 * p + 0] = 1.0f / (1.0f + expf(-x.x));
      raw[4 * p + 1] = 1.0f / (1.0f + expf(-x.y));
      raw[4 * p + 2] = 1.0f / (1.0f + expf(-x.z));
      raw[4 * p + 3] = 1.0f / (1.0f + expf(-x.w));
    } else {
      raw[4 * p + 0] = 0.f; raw[4 * p + 1] = 0.f; raw[4 * p + 2] = 0.f; raw[4 * p + 3] = 0.f;
    }
  }
  // ---- phase B: even wave builds the (idx, score) list; static raw[] idx ----
  if (h == 0) {
    int n = 0;
#pragma unroll
    for (int p = 0; p < 4; ++p) {
      unsigned mb = 0;
      if (raw[4 * p + 0] > THRESHF) mb |= 1u;
      if (raw[4 * p + 1] > THRESHF) mb |= 2u;
      if (raw[4 * p + 2] > THRESHF) mb |= 4u;
      if (raw[4 * p + 3] > THRESHF) mb |= 8u;
      const int cnt = __popc(mb);
      int inc = cnt;
#pragma unroll
      for (int o = 1; o < 64; o <<= 1) {
        int t = __shfl_up(inc, o);
        if (lane >= o) inc += t;
      }
      int off = n + inc - cnt;
      const int total = __shfl(inc, 63);
#pragma unroll
      for (int j = 0; j < 4; ++j) {
        if (mb & (1u << j)) {
          s_idx[sp][off] = (short)((p << 8) + (lane << 2) + j);
          s_val[sp][off] = raw[4 * p + j];
          ++off;
        }
      }
      n += total;
    }
    if (lane < 3) { s_idx[sp][n + lane] = 0; s_val[sp][n + lane] = 0.0f; }  // m=0 pad
    if (lane == 0) s_n[sp] = n;
  }
  __syncthreads();
  const int n = s_n[sp];

  // ---- phase C: half-column matvec, 3 rows/iter (6 float4 in flight) ----
  float4 accA = {0, 0, 0, 0}, accB = {0, 0, 0, 0};
  {
    const float4* cop = (const float4*)co_occ;
    const int f4a = (h << 7) + lane;          // h0: lane (p0)      | h1: 128+lane (p2)
    const int f4b = f4a + 64;                 // h0: 64+lane (p1)   | h1: 192+lane (p3)
    const bool gb = (h == 0) || (lane < 58);
    for (int e = 0; e < n; e += 3) {
      const int i0 = s_idx[sp][e + 0]; const float m0 = s_val[sp][e + 0];
      const int i1 = s_idx[sp][e + 1]; const float m1 = s_val[sp][e + 1];
      const int i2 = s_idx[sp][e + 2]; const float m2 = s_val[sp][e + 2];
      const float4* r0 = cop + (size_t)i0 * 250;
      const float4* r1 = cop + (size_t)i1 * 250;
      const float4* r2 = cop + (size_t)i2 * 250;
      float4 a0 = r0[f4a], b0 = r1[f4a], d0 = r2[f4a];
      float4 a1 = {0, 0, 0, 0}, b1 = {0, 0, 0, 0}, d1 = {0, 0, 0, 0};
      if (gb) { a1 = r0[f4b]; b1 = r1[f4b]; d1 = r2[f4b]; }
      accA.x += m0 * a0.x; accA.y += m0 * a0.y; accA.z += m0 * a0.z; accA.w += m0 * a0.w;
      accB.x += m0 * a1.x; accB.y += m0 * a1.y; accB.z += m0 * a1.z; accB.w += m0 * a1.w;
      accA.x += m1 * b0.x; accA.y += m1 * b0.y; accA.z += m1 * b0.z; accA.w += m1 * b0.w;
      accB.x += m1 * b1.x; accB.y += m1 * b1.y; accB.z += m1 * b1.z; accB.w += m1 * b1.w;
      accA.x += m2 * d0.x; accA.y += m2 * d0.y; accA.z += m2 * d0.z; accA.w += m2 * d0.w;
      accB.x += m2 * d1.x; accB.y += m2 * d1.y; accB.z += m2 * d1.z; accB.w += m2 * d1.w;
    }
  }
  // ---- phase D: fin for own half -> LDS (static raw[] indices per h branch) ----
  if (h == 0) {
    float4 oA, oB;
    oA.x = raw[0] + SCALEF * accA.x; oA.y = raw[1] + SCALEF * accA.y;
    oA.z = raw[2] + SCALEF * accA.z; oA.w = raw[3] + SCALEF * accA.w;
    oB.x = raw[4] + SCALEF * accB.x; oB.y = raw[5] + SCALEF * accB.y;
    oB.z = raw[6] + SCALEF * accB.z; oB.w = raw[7] + SCALEF * accB.w;
    *(float4*)&s_fin[sp][(lane << 2)] = oA;
    *(float4*)&s_fin[sp][256 + (lane << 2)] = oB;
  } else {
    float4 oA, oB;
    oA.x = raw[8] + SCALEF * accA.x;  oA.y = raw[9] + SCALEF * accA.y;
    oA.z = raw[10] + SCALEF * accA.z; oA.w = raw[11] + SCALEF * accA.w;
    oB.x = raw[12] + SCALEF * accB.x; oB.y = raw[13] + SCALEF * accB.y;
    oB.z = raw[14] + SCALEF * accB.z; oB.w = raw[15] + SCALEF * accB.w;
    *(float4*)&s_fin[sp][512 + (lane << 2)] = oA;
    if (lane < 58) *(float4*)&s_fin[sp][768 + (lane << 2)] = oB;
  }
  __syncthreads();
  if (h == 1) return;   // odd wave done; no further barriers below

  // ---- tail (R4-verbatim layout: col = lane + 64q), scores from LDS ----
  u64 key[16];
  unsigned avail = 0;
  int cnt = 0;
  u64 kb = 0;
#pragma unroll
  for (int q = 0; q < 16; ++q) {
    const int col = lane + (q << 6);
    if (col < C_SZ) {
      const float s = s_fin[sp][col];
      const u64 k = ((u64)__float_as_uint(s) << 32) | (u64)(0xFFFFFFFFu - (unsigned)col);
      key[q] = k;
      if (k > kb) kb = k;
      if (s > THRESHF) { avail |= 1u << q; cnt++; }
    } else key[q] = 0;
  }
  u64 mk = kb;
#pragma unroll
  for (int o = 32; o >= 1; o >>= 1) { u64 t = __shfl_xor(mk, o); if (t > mk) mk = t; }
  const float mxv = __uint_as_float((unsigned)(mk >> 32));
  const int mxi = (int)(0xFFFFFFFFu - (unsigned)(mk & 0xFFFFFFFFull));
#pragma unroll
  for (int o = 32; o >= 1; o >>= 1) cnt += __shfl_xor(cnt, o);
  const int nsel = cnt;
  if ((mxi & 63) == lane) avail &= ~(1u << (mxi >> 6));
  const u64* pr = packed + (size_t)mxi * RW;
  u64 h0 = pr[lane], h1 = pr[64 + lane];
  int pc = __popcll(h0) + __popcll(h1);
#pragma unroll
  for (int o = 32; o >= 1; o >>= 1) pc += __shfl_xor(pc, o);
  int i = 1;
  float last_val = mxv;
  if (nsel >= 2 && pc > 1) {
    for (;;) {
      int kt = (nsel - i < 8) ? (nsel - i) : 8;
      float cval[8];
      int cidx[8];
      u64 rl[8], rh[8];
      float lastc = last_val;
      int kv = 0;
#pragma unroll
      for (int k = 0; k < 8; ++k) {
        cval[k] = 0.0f; cidx[k] = -1;
        if (k < kt) {
          u64 lm = 0;
#pragma unroll
          for (int q = 0; q < 16; ++q)
            if (avail & (1u << q)) { if (key[q] > lm) lm = key[q]; }
          u64 ck = lm;
#pragma unroll
          for (int o = 32; o >= 1; o >>= 1) { u64 t = __shfl_xor(ck, o); if (t > ck) ck = t; }
          if (ck != 0) {
            cval[k] = __uint_as_float((unsigned)(ck >> 32));
            cidx[k] = (int)(0xFFFFFFFFu - (unsigned)(ck & 0xFFFFFFFFull));
            if ((cidx[k] & 63) == lane) avail &= ~(1u << (cidx[k] >> 6));
            lastc = cval[k];
            kv = k + 1;
          }
        }
      }
      kt = kv;
      if (kt == 0) break;
#pragma unroll
      for (int k = 0; k < 8; ++k) {
        if (k < kt) {
          const u64* rp = packed + (size_t)cidx[k] * RW;
          rl[k] = rp[lane]; rh[k] = rp[64 + lane];
        } else { rl[k] = ~0ull; rh[k] = ~0ull; }
      }
      u64 c0 = h0, c1 = h1, pk0 = 0, pk1 = 0;
#pragma unroll
      for (int k = 0; k < 8; ++k) {
        c0 &= rl[k]; c1 &= rh[k];
        const u64 p = (u64)(__popcll(c0) + __popcll(c1));
        if (k < 4) pk0 |= p << (k * 16); else pk1 |= p << ((k - 4) * 16);
      }
#pragma unroll
      for (int o = 32; o >= 1; o >>= 1) { pk0 += __shfl_xor(pk0, o); pk1 += __shfl_xor(pk1, o); }
      int kstar = -1;
      unsigned pcv = 0;
#pragma unroll
      for (int k = 0; k < 8; ++k) {
        if (k < kt && kstar < 0) {
          const unsigned f = (unsigned)(((k < 4 ? pk0 : pk1) >> ((k & 3) * 16)) & 0xFFFFull);
          if (f <= 1u) { kstar = k; pcv = f; }
        }
      }
      if (kstar >= 0) {
        float vk = 0.f, vkm1 = last_val;
#pragma unroll
        for (int k = 0; k < 8; ++k)
          if (k == kstar) { vk = cval[k]; if (k > 0) vkm1 = cval[k - 1]; }
        const int na = (pcv == 1u) ? (kstar + 1) : kstar;
#pragma unroll
        for (int k = 0; k < 8; ++k) if (k < na) { h0 &= rl[k]; h1 &= rh[k]; }
        if (pcv == 1u) { i += kstar + 1; last_val = vk; }
        else { i += kstar; last_val = vkm1; }
        break;
      }
#pragma unroll
      for (int k = 0; k < 8; ++k) if (k < kt) { h0 &= rl[k]; h1 &= rh[k]; }
      i += kt;
      last_val = lastc;
      if (i >= nsel) break;
    }
  }
  const float hit_score = (i == 1) ? mxv : last_val;

  const int c0n = __popcll(h0), c1n = __popcll(h1);
  int s0 = c0n;
#pragma unroll
  for (int o = 1; o < 64; o <<= 1) {
    int nn = __shfl_up(s0, o);
    if (lane >= o) s0 += nn;
  }
  const int tot0 = __shfl(s0, 63);
  const int pre0 = s0 - c0n;
  int s1 = c1n;
#pragma unroll
  for (int o = 1; o < 64; o <<= 1) {
    int nn = __shfl_up(s1, o);
    if (lane >= o) s1 += nn;
  }
  const int tot = tot0 + __shfl(s1, 63);
  const int pre1 = tot0 + s1 - c1n;
  {
    u64 x = h0;
    int r = pre0;
    while (x && r < 5) {
      const int bp = __ffsll((unsigned long long)x) - 1;
      out[OFF_HI + b * 5 + r] = (float)((lane << 6) + bp);
      x &= x - 1;
      ++r;
    }
    x = h1;
    r = pre1;
    while (x && r < 5) {
      const int bp = __ffsll((unsigned long long)x) - 1;
      out[OFF_HI + b * 5 + r] = (float)(((64 + lane) << 6) + bp);
      x &= x - 1;
      ++r;
    }
  }
  int fb = 0x7fffffff;
  if (c0n) fb = (lane << 6) + __ffsll((unsigned long long)h0) - 1;
  else if (c1n) fb = ((64 + lane) << 6) + __ffsll((unsigned long long)h1) - 1;
#pragma unroll
  for (int o = 32; o >= 1; o >>= 1) fb = min(fb, __shfl_xor(fb, o));
  if (lane == 0) {
    const int num_hit = tot < 5 ? tot : 5;
    for (int r = num_hit; r < 5; ++r) out[OFF_HI + b * 5 + r] = -1.0f;
    out[OFF_HS + b] = hit_score;
    const float ci0 = out[OFF_CI + b * 5];
    const float cs0 = out[OFF_CS + b * 5];
    out[OFF_C1 + b] = (num_hit == 1) ? (float)fb : ci0;
    out[OFF_C2 + b] = (cs0 < 0.85f && num_hit == 1) ? (float)fb : ci0;
  }
}

extern "C" void kernel_launch(void* const* d_in, const int* in_sizes, int n_in,
                              void* d_out, int out_size, void* d_ws, size_t ws_size,
                              hipStream_t stream) {
  (void)in_sizes; (void)n_in; (void)out_size; (void)ws_size;
  const float* class_logits = (const float*)d_in[0];
  const float* compo_logits = (const float*)d_in[1];
  const float* co_occ = (const float*)d_in[2];
  const int* mat = (const int*)d_in[3];
  float* out = (float*)d_out;
  u64* packed = (u64*)d_ws;  // 1 MB

  pack_kernel<<<C_SZ, 256, 0, stream>>>(mat, packed);
  class_topk_kernel<<<B_SZ, 256, 0, stream>>>(class_logits, out);
  decode_kernel<<<B_SZ / 2, 256, 0, stream>>>(compo_logits, co_occ, packed, out);
}

// Round 16
// 133.360 us; speedup vs baseline: 1.3081x; 1.1881x over previous
//
#include <hip/hip_runtime.h>
#include <cstdint>
#include <cstddef>

typedef unsigned long long u64;

#define B_SZ 4096
#define C_SZ 1000
#define V_SZ 8000
#define RW 128              // padded row stride in u64 (125 used, rest zero)
#define THRESHF 0.8f
#define SCALEF 0.1f

#define OFF_CI 0
#define OFF_CS (B_SZ * 5)
#define OFF_HI (2 * B_SZ * 5)
#define OFF_HS (3 * B_SZ * 5)
#define OFF_C1 (3 * B_SZ * 5 + B_SZ)
#define OFF_C2 (3 * B_SZ * 5 + 2 * B_SZ)

// ---------------- pack matrix rows into bitmasks ----------------
__global__ __launch_bounds__(256) void pack_kernel(const int* __restrict__ mat,
                                                   u64* __restrict__ packed) {
  const int c = blockIdx.x;
  const int tid = threadIdx.x;
  const int lane = tid & 63;
  const int wv = tid >> 6;
  const int* row = mat + (size_t)c * V_SZ;
  for (int base = 0; base < 8192; base += 256) {
    const int k = base + tid;
    int v = 0;
    if (k < V_SZ) v = row[k];
    u64 msk = __ballot(v != 0);
    if (lane == 0) packed[(size_t)c * RW + ((base >> 6) + wv)] = msk;
  }
}

// ---------------- class softmax + top5 (float4 loads) ----------------
__global__ __launch_bounds__(256) void class_topk_kernel(const float* __restrict__ logits,
                                                         float* __restrict__ out) {
  const int b = blockIdx.x;
  const int tid = threadIdx.x;
  const int lane = tid & 63;
  const int wv = tid >> 6;
  const float* row = logits + (size_t)b * V_SZ;
  float v[32];
#pragma unroll
  for (int f = 0; f < 8; ++f) {
    const int base = (f << 10) + (tid << 2);
    if (base < V_SZ) {
      float4 x = *(const float4*)(row + base);
      v[4 * f + 0] = x.x; v[4 * f + 1] = x.y; v[4 * f + 2] = x.z; v[4 * f + 3] = x.w;
    } else {
      v[4 * f + 0] = -INFINITY; v[4 * f + 1] = -INFINITY;
      v[4 * f + 2] = -INFINITY; v[4 * f + 3] = -INFINITY;
    }
  }
  __shared__ float sred[4];
  __shared__ int sredi[4];
  float lm = -INFINITY;
#pragma unroll
  for (int q = 0; q < 32; ++q) lm = fmaxf(lm, v[q]);
#pragma unroll
  for (int o = 32; o >= 1; o >>= 1) lm = fmaxf(lm, __shfl_xor(lm, o));
  if (lane == 0) sred[wv] = lm;
  __syncthreads();
  const float m = fmaxf(fmaxf(sred[0], sred[1]), fmaxf(sred[2], sred[3]));
  float ls = 0.f;
#pragma unroll
  for (int q = 0; q < 32; ++q) ls += expf(v[q] - m);
#pragma unroll
  for (int o = 32; o >= 1; o >>= 1) ls += __shfl_xor(ls, o);
  __syncthreads();
  if (lane == 0) sred[wv] = ls;
  __syncthreads();
  const float ssum = sred[0] + sred[1] + sred[2] + sred[3];
  for (int r = 0; r < 5; ++r) {
    float bv = -INFINITY;
    int bi = 0;
#pragma unroll
    for (int q = 0; q < 32; ++q) {
      const int idx = ((q >> 2) << 10) + (tid << 2) + (q & 3);
      if (v[q] > bv) { bv = v[q]; bi = idx; }
    }
#pragma unroll
    for (int o = 32; o >= 1; o >>= 1) {
      float ov = __shfl_xor(bv, o);
      int oi = __shfl_xor(bi, o);
      if (ov > bv || (ov == bv && oi < bi)) { bv = ov; bi = oi; }
    }
    __syncthreads();
    if (lane == 0) { sred[wv] = bv; sredi[wv] = bi; }
    __syncthreads();
    bv = sred[0]; bi = sredi[0];
#pragma unroll
    for (int w = 1; w < 4; ++w) {
      if (sred[w] > bv || (sred[w] == bv && sredi[w] < bi)) { bv = sred[w]; bi = sredi[w]; }
    }
    if (((bi & 1023) >> 2) == tid) {
      const int sl = ((bi >> 10) << 2) | (bi & 3);
#pragma unroll
      for (int q = 0; q < 32; ++q)
        if (q == sl) v[q] = -INFINITY;
    }
    if (tid == 0) {
      out[OFF_CI + b * 5 + r] = (float)bi;
      out[OFF_CS + b * 5 + r] = expf(bv - m) / ssum;
    }
  }
}

// ---------------- decode: one WAVE per sample; 4-row-batched matvec ----------------
__global__ __launch_bounds__(256, 4) void decode_kernel(const float* __restrict__ compo_logits,
                                                        const float* __restrict__ co_occ,
                                                        const u64* __restrict__ packed,
                                                        float* __restrict__ out) {
  const int tid = threadIdx.x;
  const int lane = tid & 63;
  const int w = tid >> 6;
  const int b = blockIdx.x * 4 + w;
  __shared__ short s_idx[4][512];   // ascending selected rows, per wave
  __shared__ float s_val[4][512];   // matching sigmoid scores

  // ---- phase A: sigmoid into regs; layout col = 4*lane + (q&3) + 256*(q>>2) ----
  const float4* lg4 = (const float4*)(compo_logits + (size_t)b * C_SZ);
  float raw[16];
#pragma unroll
  for (int p = 0; p < 4; ++p) {
    const int fi = lane + (p << 6);   // float4 index within row
    if (fi < 250) {
      float4 x = lg4[fi];
      raw[4 * p + 0] = 1.0f / (1.0f + expf(-x.x));
      raw[4 * p + 1] = 1.0f / (1.0f + expf(-x.y));
      raw[4 * p + 2] = 1.0f / (1.0f + expf(-x.z));
      raw[4 * p + 3] = 1.0f / (1.0f + expf(-x.w));
    } else {
      raw[4 * p + 0] = 0.f; raw[4 * p + 1] = 0.f; raw[4 * p + 2] = 0.f; raw[4 * p + 3] = 0.f;
    }
  }
  // ---- phase B: prefix-scan compaction of (idx, score), ascending; static raw[] idx ----
  int n = 0;
#pragma unroll
  for (int p = 0; p < 4; ++p) {
    unsigned mb = 0;
    if (raw[4 * p + 0] > THRESHF) mb |= 1u;
    if (raw[4 * p + 1] > THRESHF) mb |= 2u;
    if (raw[4 * p + 2] > THRESHF) mb |= 4u;
    if (raw[4 * p + 3] > THRESHF) mb |= 8u;
    const int cnt = __popc(mb);
    int inc = cnt;
#pragma unroll
    for (int o = 1; o < 64; o <<= 1) {
      int t = __shfl_up(inc, o);
      if (lane >= o) inc += t;
    }
    int off = n + inc - cnt;
    const int total = __shfl(inc, 63);
#pragma unroll
    for (int j = 0; j < 4; ++j) {
      if (mb & (1u << j)) {
        s_idx[w][off] = (short)((p << 8) + (lane << 2) + j);
        s_val[w][off] = raw[4 * p + j];   // static index
        ++off;
      }
    }
    n += total;
  }
  // pad to batch boundary: (idx=0, val=0) entries -> FMA * 0 = exact no-op
  if (lane < 4) { s_idx[w][n + lane] = 0; s_val[w][n + lane] = 0.0f; }

  // ---- phase C: matvec, 4 rows per iteration (4-deep MLP, ascending-e order) ----
  float4 acc0 = {0, 0, 0, 0}, acc1 = {0, 0, 0, 0}, acc2 = {0, 0, 0, 0}, acc3 = {0, 0, 0, 0};
  {
    const float4* cop = (const float4*)co_occ;
    const int l0 = lane, l1 = lane + 64, l2 = lane + 128, l3 = lane + 192;
    const bool g3 = lane < 58;
    for (int e = 0; e < n; e += 4) {
      const int i0 = s_idx[w][e + 0]; const float m0 = s_val[w][e + 0];
      const int i1 = s_idx[w][e + 1]; const float m1 = s_val[w][e + 1];
      const int i2 = s_idx[w][e + 2]; const float m2 = s_val[w][e + 2];
      const int i3 = s_idx[w][e + 3]; const float m3 = s_val[w][e + 3];
      const float4* r0 = cop + (size_t)i0 * 250;
      const float4* r1 = cop + (size_t)i1 * 250;
      const float4* r2 = cop + (size_t)i2 * 250;
      const float4* r3 = cop + (size_t)i3 * 250;
      float4 a0 = r0[l0], a1 = r0[l1], a2 = r0[l2];
      float4 b0 = r1[l0], b1 = r1[l1], b2 = r1[l2];
      float4 d0 = r2[l0], d1 = r2[l1], d2 = r2[l2];
      float4 e0 = r3[l0], e1 = r3[l1], e2 = r3[l2];
      float4 a3 = {0, 0, 0, 0}, b3 = {0, 0, 0, 0}, d3 = {0, 0, 0, 0}, e3 = {0, 0, 0, 0};
      if (g3) { a3 = r0[l3]; b3 = r1[l3]; d3 = r2[l3]; e3 = r3[l3]; }
      // row e+0
      acc0.x += m0 * a0.x; acc0.y += m0 * a0.y; acc0.z += m0 * a0.z; acc0.w += m0 * a0.w;
      acc1.x += m0 * a1.x; acc1.y += m0 * a1.y; acc1.z += m0 * a1.z; acc1.w += m0 * a1.w;
      acc2.x += m0 * a2.x; acc2.y += m0 * a2.y; acc2.z += m0 * a2.z; acc2.w += m0 * a2.w;
      acc3.x += m0 * a3.x; acc3.y += m0 * a3.y; acc3.z += m0 * a3.z; acc3.w += m0 * a3.w;
      // row e+1
      acc0.x += m1 * b0.x; acc0.y += m1 * b0.y; acc0.z += m1 * b0.z; acc0.w += m1 * b0.w;
      acc1.x += m1 * b1.x; acc1.y += m1 * b1.y; acc1.z += m1 * b1.z; acc1.w += m1 * b1.w;
      acc2.x += m1 * b2.x; acc2.y += m1 * b2.y; acc2.z += m1 * b2.z; acc2.w += m1 * b2.w;
      acc3.x += m1 * b3.x; acc3.y += m1 * b3.y; acc3.z += m1 * b3.z; acc3.w += m1 * b3.w;
      // row e+2
      acc0.x += m2 * d0.x; acc0.y += m2 * d0.y; acc0.z += m2 * d0.z; acc0.w += m2 * d0.w;
      acc1.x += m2 * d1.x; acc1.y += m2 * d1.y; acc1.z += m2 * d1.z; acc1.w += m2 * d1.w;
      acc2.x += m2 * d2.x; acc2.y += m2 * d2.y; acc2.z += m2 * d2.z; acc2.w += m2 * d2.w;
      acc3.x += m2 * d3.x; acc3.y += m2 * d3.y; acc3.z += m2 * d3.z; acc3.w += m2 * d3.w;
      // row e+3
      acc0.x += m3 * e0.x; acc0.y += m3 * e0.y; acc0.z += m3 * e0.z; acc0.w += m3 * e0.w;
      acc1.x += m3 * e1.x; acc1.y += m3 * e1.y; acc1.z += m3 * e1.z; acc1.w += m3 * e1.w;
      acc2.x += m3 * e2.x; acc2.y += m3 * e2.y; acc2.z += m3 * e2.z; acc2.w += m3 * e2.w;
      acc3.x += m3 * e3.x; acc3.y += m3 * e3.y; acc3.z += m3 * e3.z; acc3.w += m3 * e3.w;
    }
  }
  // ---- phase D: final scores in regs; build u64 keys ----
  float fin[16];
  fin[0] = raw[0] + SCALEF * acc0.x;  fin[1] = raw[1] + SCALEF * acc0.y;
  fin[2] = raw[2] + SCALEF * acc0.z;  fin[3] = raw[3] + SCALEF * acc0.w;
  fin[4] = raw[4] + SCALEF * acc1.x;  fin[5] = raw[5] + SCALEF * acc1.y;
  fin[6] = raw[6] + SCALEF * acc1.z;  fin[7] = raw[7] + SCALEF * acc1.w;
  fin[8] = raw[8] + SCALEF * acc2.x;  fin[9] = raw[9] + SCALEF * acc2.y;
  fin[10] = raw[10] + SCALEF * acc2.z; fin[11] = raw[11] + SCALEF * acc2.w;
  fin[12] = raw[12] + SCALEF * acc3.x; fin[13] = raw[13] + SCALEF * acc3.y;
  fin[14] = raw[14] + SCALEF * acc3.z; fin[15] = raw[15] + SCALEF * acc3.w;

  u64 key[16];
  unsigned avail = 0;
  int cnt = 0;
  u64 kb = 0;
#pragma unroll
  for (int q = 0; q < 16; ++q) {
    const int col = (lane << 2) + (q & 3) + ((q >> 2) << 8);
    if (col < C_SZ) {
      const float f = fin[q];
      const u64 k = ((u64)__float_as_uint(f) << 32) | (u64)(0xFFFFFFFFu - (unsigned)col);
      key[q] = k;
      if (k > kb) kb = k;
      if (f > THRESHF) { avail |= 1u << q; cnt++; }
    } else key[q] = 0;
  }
  // ---- tail (R4/R6/R7/R8-validated logic) ----
  u64 mk = kb;
#pragma unroll
  for (int o = 32; o >= 1; o >>= 1) { u64 t = __shfl_xor(mk, o); if (t > mk) mk = t; }
  const float mxv = __uint_as_float((unsigned)(mk >> 32));
  const int mxi = (int)(0xFFFFFFFFu - (unsigned)(mk & 0xFFFFFFFFull));
#pragma unroll
  for (int o = 32; o >= 1; o >>= 1) cnt += __shfl_xor(cnt, o);
  const int nsel = cnt;
  if (((mxi >> 2) & 63) == lane) avail &= ~(1u << ((mxi & 3) | ((mxi >> 8) << 2)));
  const u64* pr = packed + (size_t)mxi * RW;
  u64 h0 = pr[lane], h1 = pr[64 + lane];
  int pc = __popcll(h0) + __popcll(h1);
#pragma unroll
  for (int o = 32; o >= 1; o >>= 1) pc += __shfl_xor(pc, o);
  int ii = 1;
  float last_val = mxv;
  if (nsel >= 2 && pc > 1) {
    for (;;) {
      int kt = (nsel - ii < 8) ? (nsel - ii) : 8;
      float cval[8];
      int cidx[8];
      u64 rl[8], rh[8];
      float lastc = last_val;
      int kv = 0;
#pragma unroll
      for (int k = 0; k < 8; ++k) {
        cval[k] = 0.0f; cidx[k] = -1;
        if (k < kt) {
          u64 lm = 0;
#pragma unroll
          for (int q = 0; q < 16; ++q)
            if (avail & (1u << q)) { if (key[q] > lm) lm = key[q]; }
          u64 ck = lm;
#pragma unroll
          for (int o = 32; o >= 1; o >>= 1) { u64 t = __shfl_xor(ck, o); if (t > ck) ck = t; }
          if (ck != 0) {
            cval[k] = __uint_as_float((unsigned)(ck >> 32));
            cidx[k] = (int)(0xFFFFFFFFu - (unsigned)(ck & 0xFFFFFFFFull));
            if (((cidx[k] >> 2) & 63) == lane)
              avail &= ~(1u << ((cidx[k] & 3) | ((cidx[k] >> 8) << 2)));
            lastc = cval[k];
            kv = k + 1;
          }
        }
      }
      kt = kv;
      if (kt == 0) break;
#pragma unroll
      for (int k = 0; k < 8; ++k) {
        if (k < kt) {
          const u64* rp2 = packed + (size_t)cidx[k] * RW;
          rl[k] = rp2[lane]; rh[k] = rp2[64 + lane];
        } else { rl[k] = ~0ull; rh[k] = ~0ull; }
      }
      u64 c0 = h0, c1 = h1, pk0 = 0, pk1 = 0;
#pragma unroll
      for (int k = 0; k < 8; ++k) {
        c0 &= rl[k]; c1 &= rh[k];
        const u64 p = (u64)(__popcll(c0) + __popcll(c1));
        if (k < 4) pk0 |= p << (k * 16); else pk1 |= p << ((k - 4) * 16);
      }
#pragma unroll
      for (int o = 32; o >= 1; o >>= 1) { pk0 += __shfl_xor(pk0, o); pk1 += __shfl_xor(pk1, o); }
      int kstar = -1;
      unsigned pcv = 0;
#pragma unroll
      for (int k = 0; k < 8; ++k) {
        if (k < kt && kstar < 0) {
          const unsigned f = (unsigned)(((k < 4 ? pk0 : pk1) >> ((k & 3) * 16)) & 0xFFFFull);
          if (f <= 1u) { kstar = k; pcv = f; }
        }
      }
      if (kstar >= 0) {
        float vk = 0.f, vkm1 = last_val;
#pragma unroll
        for (int k = 0; k < 8; ++k)
          if (k == kstar) { vk = cval[k]; if (k > 0) vkm1 = cval[k - 1]; }
        const int na = (pcv == 1u) ? (kstar + 1) : kstar;
#pragma unroll
        for (int k = 0; k < 8; ++k) if (k < na) { h0 &= rl[k]; h1 &= rh[k]; }
        if (pcv == 1u) { ii += kstar + 1; last_val = vk; }
        else { ii += kstar; last_val = vkm1; }
        break;
      }
#pragma unroll
      for (int k = 0; k < 8; ++k) if (k < kt) { h0 &= rl[k]; h1 &= rh[k]; }
      ii += kt;
      last_val = lastc;
      if (ii >= nsel) break;
    }
  }
  const float hit_score = (ii == 1) ? mxv : last_val;

  // ---- emission ----
  const int c0n = __popcll(h0), c1n = __popcll(h1);
  int s0 = c0n;
#pragma unroll
  for (int o = 1; o < 64; o <<= 1) {
    int nn = __shfl_up(s0, o);
    if (lane >= o) s0 += nn;
  }
  const int tot0 = __shfl(s0, 63);
  const int pre0 = s0 - c0n;
  int s1 = c1n;
#pragma unroll
  for (int o = 1; o < 64; o <<= 1) {
    int nn = __shfl_up(s1, o);
    if (lane >= o) s1 += nn;
  }
  const int tot = tot0 + __shfl(s1, 63);
  const int pre1 = tot0 + s1 - c1n;
  {
    u64 x = h0;
    int r = pre0;
    while (x && r < 5) {
      const int bp = __ffsll((unsigned long long)x) - 1;
      out[OFF_HI + b * 5 + r] = (float)((lane << 6) + bp);
      x &= x - 1;
      ++r;
    }
    x = h1;
    r = pre1;
    while (x && r < 5) {
      const int bp = __ffsll((unsigned long long)x) - 1;
      out[OFF_HI + b * 5 + r] = (float)(((64 + lane) << 6) + bp);
      x &= x - 1;
      ++r;
    }
  }
  int fb = 0x7fffffff;
  if (c0n) fb = (lane << 6) + __ffsll((unsigned long long)h0) - 1;
  else if (c1n) fb = ((64 + lane) << 6) + __ffsll((unsigned long long)h1) - 1;
#pragma unroll
  for (int o = 32; o >= 1; o >>= 1) fb = min(fb, __shfl_xor(fb, o));
  if (lane == 0) {
    const int num_hit = tot < 5 ? tot : 5;
    for (int r = num_hit; r < 5; ++r) out[OFF_HI + b * 5 + r] = -1.0f;
    out[OFF_HS + b] = hit_score;
    const float ci0 = out[OFF_CI + b * 5];
    const float cs0 = out[OFF_CS + b * 5];
    out[OFF_C1 + b] = (num_hit == 1) ? (float)fb : ci0;
    out[OFF_C2 + b] = (cs0 < 0.85f && num_hit == 1) ? (float)fb : ci0;
  }
}

extern "C" void kernel_launch(void* const* d_in, const int* in_sizes, int n_in,
                              void* d_out, int out_size, void* d_ws, size_t ws_size,
                              hipStream_t stream) {
  (void)in_sizes; (void)n_in; (void)out_size; (void)ws_size;
  const float* class_logits = (const float*)d_in[0];
  const float* compo_logits = (const float*)d_in[1];
  const float* co_occ = (const float*)d_in[2];
  const int* mat = (const int*)d_in[3];
  float* out = (float*)d_out;
  u64* packed = (u64*)d_ws;  // 1 MB

  pack_kernel<<<C_SZ, 256, 0, stream>>>(mat, packed);
  class_topk_kernel<<<B_SZ, 256, 0, stream>>>(class_logits, out);
  decode_kernel<<<B_SZ / 4, 256, 0, stream>>>(compo_logits, co_occ, packed, out);
}